// Round 16
// baseline (162.030 us; speedup 1.0000x reference)
//
#include <hip/hip_runtime.h>

#define DI __device__ __forceinline__

typedef __attribute__((ext_vector_type(8))) short s16x8;
typedef __attribute__((ext_vector_type(4))) short s16x4;
typedef __attribute__((ext_vector_type(4))) float f32x4;

DI unsigned short f2bf(float f){
  unsigned u = __float_as_uint(f);
  u = (u + 0x7FFFu + ((u >> 16) & 1u)) >> 16;
  return (unsigned short)u;
}
DI float bf2f(unsigned short h){
  return __uint_as_float(((unsigned)h) << 16);
}
DI float exp2i(float x){ float r; asm("v_exp_f32 %0, %1" : "=v"(r) : "v"(x)); return r; }

DI void gll16(const void* g, void* l){
  __builtin_amdgcn_global_load_lds((const __attribute__((address_space(1))) void*)g,
                                   (__attribute__((address_space(3))) void*)l, 16, 0, 0);
}

#define VMCNT(n) asm volatile("s_waitcnt vmcnt(" #n ")" ::: "memory")
#define SB() __builtin_amdgcn_sched_barrier(0)

// ---------------- merged prep: x fp32->bf16, Wa^T, Wp^T ----------------
__global__ void prep_kernel(const float* __restrict__ x, unsigned short* __restrict__ xb,
                            const float* __restrict__ Wa, unsigned short* __restrict__ WaT,
                            const float* __restrict__ Wp, unsigned short* __restrict__ WpT)
{
  __shared__ float t[32][33];
  int blk = blockIdx.x, tid = threadIdx.x;
  if (blk < 2048){
    int i = blk * 256 + tid;
    const float4* p = (const float4*)x + (size_t)i * 2;
    float4 a = p[0], b = p[1];
    s16x8 o;
    o[0] = (short)f2bf(a.x); o[1] = (short)f2bf(a.y); o[2] = (short)f2bf(a.z); o[3] = (short)f2bf(a.w);
    o[4] = (short)f2bf(b.x); o[5] = (short)f2bf(b.y); o[6] = (short)f2bf(b.z); o[7] = (short)f2bf(b.w);
    ((s16x8*)xb)[i] = o;
  } else {
    const float* in; unsigned short* out; int R, C, bx, by;
    if (blk < 5120){
      int k = blk - 2048; in = Wa; out = WaT; R = 1024; C = 3072; bx = k % 96; by = k / 96;
    } else {
      int k = blk - 5120; in = Wp; out = WpT; R = 1024; C = 1024; bx = k % 32; by = k / 32;
    }
    int c0 = bx * 32, r0 = by * 32;
    int tx = tid & 31, ty = tid >> 5;  // 32 x 8
    #pragma unroll
    for (int i = 0; i < 4; i++)
      t[ty + i*8][tx] = in[(size_t)(r0 + ty + i*8) * C + c0 + tx];
    __syncthreads();
    #pragma unroll
    for (int i = 0; i < 4; i++)
      out[(size_t)(c0 + ty + i*8) * R + r0 + tx] = f2bf(t[tx][ty + i*8]);
  }
}

// ---------------- GEMM (m97 structure): C[M x N] = A[M x K] * Wt[N x K]^T + bias ----------------
template<int MODE, int BM>
__launch_bounds__(256)
__global__ void gemm_kernel(const unsigned short* __restrict__ A,
                            const unsigned short* __restrict__ Wt,
                            const float* __restrict__ bias,
                            int N,
                            unsigned short* __restrict__ qb,
                            unsigned short* __restrict__ kb,
                            unsigned short* __restrict__ vt,
                            float* __restrict__ out)
{
  constexpr int MI = BM / 32;
  constexpr int AC = BM / 32;
  const int K = 1024;
  __shared__ __align__(16) unsigned short Sm[BM*64 + 128*64];
  unsigned short* As = Sm;
  unsigned short* Bs = Sm + BM*64;

  int lin = blockIdx.y * gridDim.x + blockIdx.x;
  int chunk = (gridDim.x * gridDim.y) >> 3;
  int v = (lin & 7) * chunk + (lin >> 3);
  int bx = v % gridDim.x, by = v / gridDim.x;
  int m0 = by * BM, n0 = bx * 128;

  int tid = threadIdx.x;
  int lane = tid & 63, w = tid >> 6;
  int row_l = lane & 15, kgrp = lane >> 4;
  int wm = (w >> 1) * (MI * 16), wn = (w & 1) * 64;

  const unsigned short* asrc[AC];
  const unsigned short* bsrc[4];
  int ldsoA[AC], ldsoB[4];
  int chnk = (lane & 7) ^ (lane >> 3);
  #pragma unroll
  for (int c4 = 0; c4 < AC; c4++){
    int r = c4*32 + w*8 + (lane >> 3);
    asrc[c4] = A + (size_t)(m0 + r) * K + chnk*8;
    ldsoA[c4] = (c4*32 + w*8) * 64;
  }
  #pragma unroll
  for (int c4 = 0; c4 < 4; c4++){
    int r = c4*32 + w*8 + (lane >> 3);
    bsrc[c4] = Wt + (size_t)(n0 + r) * K + chnk*8;
    ldsoB[c4] = (c4*32 + w*8) * 64;
  }
  int eA[MI], eB[4];
  #pragma unroll
  for (int i = 0; i < MI; i++){
    int ra = wm + i*16 + row_l;
    eA[i] = (ra*64 + kgrp*8) ^ ((ra & 7) << 3);
  }
  #pragma unroll
  for (int i = 0; i < 4; i++){
    int rb = wn + i*16 + row_l;
    eB[i] = (rb*64 + kgrp*8) ^ ((rb & 7) << 3);
  }

  f32x4 acc[MI][4];
  #pragma unroll
  for (int i = 0; i < MI; i++)
    #pragma unroll
    for (int j = 0; j < 4; j++)
      acc[i][j] = (f32x4){0.f, 0.f, 0.f, 0.f};

  for (int k0 = 0; k0 < K; k0 += 64){
    #pragma unroll
    for (int c4 = 0; c4 < AC; c4++)
      gll16(asrc[c4] + k0, (void*)(As + ldsoA[c4]));
    #pragma unroll
    for (int c4 = 0; c4 < 4; c4++)
      gll16(bsrc[c4] + k0, (void*)(Bs + ldsoB[c4]));
    __syncthreads();
    #pragma unroll
    for (int kc = 0; kc < 2; kc++){
      s16x8 af[MI], bfr[4];
      #pragma unroll
      for (int mi = 0; mi < MI; mi++)
        af[mi] = *(const s16x8*)&As[eA[mi] ^ (kc*32)];
      #pragma unroll
      for (int ni = 0; ni < 4; ni++)
        bfr[ni] = *(const s16x8*)&Bs[eB[ni] ^ (kc*32)];
      #pragma unroll
      for (int mi = 0; mi < MI; mi++)
        #pragma unroll
        for (int ni = 0; ni < 4; ni++)
          acc[mi][ni] = __builtin_amdgcn_mfma_f32_16x16x32_bf16(af[mi], bfr[ni], acc[mi][ni], 0, 0, 0);
    }
    __syncthreads();
  }

  if (MODE == 0){
    unsigned long long* ldsT = (unsigned long long*)Sm;   // [np 0..127][mq 0..31] u64
    #pragma unroll
    for (int mi = 0; mi < MI; mi++){
      #pragma unroll
      for (int ni = 0; ni < 4; ni++){
        int np = wn + ni*16 + row_l;
        int gc = n0 + np;
        int hh = gc / 192, cc = gc % 192;
        float bia = bias[gc];
        if (cc < 128){
          #pragma unroll
          for (int j = 0; j < 4; j++){
            int gr = m0 + wm + mi*16 + kgrp*4 + j;
            float v2 = acc[mi][ni][j] + bia;
            if (cc < 64){
              qb[(size_t)gr * 1024 + hh*64 + cc] = f2bf(v2 * 1.44269504f);
            } else {
              int d = cc - 64; int b = gr >> 11, s = gr & 2047;
              int kt = s >> 6, kk = s & 63;
              kb[(size_t)((b*16 + hh)*32 + kt) * 4096 + ((kk*64 + d) ^ ((kk & 7) << 3))] = f2bf(v2);
            }
          }
        } else {
          float v0 = acc[mi][ni][0] + bia, v1 = acc[mi][ni][1] + bia;
          float v2 = acc[mi][ni][2] + bia, v3 = acc[mi][ni][3] + bia;
          unsigned lo, hi;
          asm("v_cvt_pk_bf16_f32 %0, %1, %2" : "=v"(lo) : "v"(v0), "v"(v1));
          asm("v_cvt_pk_bf16_f32 %0, %1, %2" : "=v"(hi) : "v"(v2), "v"(v3));
          int mq = (wm + mi*16 + kgrp*4) >> 2;
          ldsT[np*32 + (mq ^ ((np & 7) << 2))] = ((unsigned long long)hi << 32) | (unsigned long long)lo;
        }
      }
    }
    __syncthreads();
    int bb = m0 >> 11, s_base = m0 & 2047;
    for (int item = tid; item < 2048; item += 256){
      int np = item >> 4;
      int gcv = n0 + np;
      int cc = gcv % 192;
      if (cc < 128) continue;
      int d = cc - 128, hh = gcv / 192;
      int sub = (item >> 3) & 1;
      int c = item & 7;
      int mq0 = sub*16 + c*2;
      s16x8 val = *(const s16x8*)&Sm[np*128 + ((mq0 ^ ((np & 7) << 2)) << 2)];
      size_t base = ((size_t)((bb*16 + hh)*32) + (s_base >> 6) + sub) * 4096 + d*64 + ((c ^ (d & 7)) << 3);
      *(s16x8*)&vt[base] = val;
    }
  } else {
    #pragma unroll
    for (int mi = 0; mi < MI; mi++){
      #pragma unroll
      for (int ni = 0; ni < 4; ni++){
        #pragma unroll
        for (int j = 0; j < 4; j++){
          int gr = m0 + wm + mi*16 + kgrp*4 + j;
          int gc = n0 + wn + ni*16 + row_l;
          out[(size_t)gr * N + gc] = acc[mi][ni][j] + bias[gc];
        }
      }
    }
  }
}

// ---------------- V suffix sums (64-key granularity): sufv[bh][t in 0..32][64d] ----------------
__global__ void sufv_kernel(const unsigned short* __restrict__ vt, float* __restrict__ sufv){
  __shared__ float tot[4][64];
  int bh = blockIdx.x;                 // 32
  int tid = threadIdx.x;               // 256
  int tq = tid >> 6, d = tid & 63;
  const unsigned short* base = vt + (size_t)bh * 32 * 4096;
  float s[8];
  float run = 0.f;
  for (int j = 7; j >= 0; j--){
    int t = tq*8 + j;
    float rs = 0.f;
    #pragma unroll
    for (int c = 0; c < 8; c++){
      int idx = (d*64 + c*8) ^ ((d & 7) << 3);
      s16x8 v = *(const s16x8*)&base[(size_t)t*4096 + idx];
      #pragma unroll
      for (int e = 0; e < 8; e++) rs += bf2f((unsigned short)v[e]);
    }
    run += rs; s[j] = run;
  }
  tot[tq][d] = run;
  __syncthreads();
  float carry = 0.f;
  for (int t2 = tq+1; t2 < 4; t2++) carry += tot[t2][d];
  #pragma unroll
  for (int j = 0; j < 8; j++)
    sufv[((size_t)bh*33 + tq*8 + j)*64 + d] = s[j] + carry;
  if (tid < 64) sufv[((size_t)bh*33 + 32)*64 + tid] = 0.f;
}

// ---------------- D-pass v3: pairwise heads, ring-4 slots, stage pair t+1 POST-barrier ----------------
// 8 barrier-phases. Iter t computes heads 2t,2t+1 from slots (2t)&3,(2t+1)&3; post-barrier(t)
// stages heads 2t+2,2t+3 into the OTHER pair-slots (read at iter t-1, barrier-protected).
// VMCNT (ops newer than stages(pair t)): t=0 -> 8 (qf4+qn4); t=1..6 -> 4 (qn); t=7 -> 0.
__launch_bounds__(256)
__global__ void dpass_kernel(const unsigned short* __restrict__ qbuf,
                             const unsigned short* __restrict__ kb,
                             unsigned short* __restrict__ invb)
{
  __shared__ unsigned short Kst[4][4096];
  int bid = blockIdx.x;                       // 1056 = 8 * 132
  int blk = (bid & 7) * 132 + (bid >> 3);     // XCD swizzle (bijective)
  int b = blk / 528, t0 = blk % 528;
  int kt = (int)(32.5f - sqrtf(1056.25f - 2.f*t0));
  while (kt*(65-kt)/2 > t0) kt--;
  while ((kt+1)*(64-kt)/2 <= t0) kt++;
  int qt = kt + (t0 - kt*(65-kt)/2);

  int tid = threadIdx.x, lane = tid & 63, w = tid >> 6;
  int row_l = lane & 15, kgrp = lane >> 4;

  const unsigned short* ktb = kb + ((size_t)(b*16)*32 + kt) * 4096;
  int sgoff = (w*128 + lane)*8;

  auto stage = [&](int hh){
    const unsigned short* src = ktb + (size_t)hh * 131072;
    gll16(src + sgoff,       (void*)(&Kst[hh & 3][0] + w*1024));
    gll16(src + sgoff + 512, (void*)(&Kst[hh & 3][0] + w*1024 + 512));
  };

  int e0[4];
  #pragma unroll
  for (int ks = 0; ks < 4; ks++){
    int row = ks*16 + row_l;
    e0[ks] = (row*64 + kgrp*8) ^ ((row & 7) << 3);
  }

  const unsigned short* qrow_p = qbuf + (size_t)(b*2048 + qt*64 + w*16 + row_l) * 1024;

  // prologue: stage pair0 (4 vm), q-frags for pair0 (4 vm)
  stage(0); stage(1);
  s16x8 qa0 = *(const s16x8*)&qrow_p[kgrp*8];
  s16x8 qa1 = *(const s16x8*)&qrow_p[32 + kgrp*8];
  s16x8 qb0 = *(const s16x8*)&qrow_p[64 + kgrp*8];
  s16x8 qb1 = *(const s16x8*)&qrow_p[64 + 32 + kgrp*8];
  SB();

  f32x4 esum[4];
  #pragma unroll
  for (int ks = 0; ks < 4; ks++) esum[ks] = (f32x4){0.f,0.f,0.f,0.f};

  for (int t = 0; t < 8; t++){
    int h = 2*t;
    s16x8 qn0, qn1, qn2, qn3;
    if (t < 7){
      qn0 = *(const s16x8*)&qrow_p[(h+2)*64 + kgrp*8];
      qn1 = *(const s16x8*)&qrow_p[(h+2)*64 + 32 + kgrp*8];
      qn2 = *(const s16x8*)&qrow_p[(h+3)*64 + kgrp*8];
      qn3 = *(const s16x8*)&qrow_p[(h+3)*64 + 32 + kgrp*8];  // 4 vm
    }
    SB();
    if (t == 0)     VMCNT(8);
    else if (t < 7) VMCNT(4);
    else            VMCNT(0);
    SB();
    __builtin_amdgcn_s_barrier();
    SB();
    if (t < 7){ stage(h+2); stage(h+3); }   // POST-barrier into pair-slots read at iter t-1
    SB();

    const unsigned short* kl0 = &Kst[h & 3][0];
    const unsigned short* kl1 = &Kst[(h+1) & 3][0];
    #pragma unroll
    for (int ks = 0; ks < 4; ks++){
      s16x8 a0 = *(const s16x8*)&kl0[e0[ks]];
      s16x8 a1 = *(const s16x8*)&kl0[e0[ks] ^ 32];
      f32x4 sc = __builtin_amdgcn_mfma_f32_16x16x32_bf16(a0, qa0, (f32x4){0.f,0.f,0.f,0.f}, 0, 0, 0);
      sc = __builtin_amdgcn_mfma_f32_16x16x32_bf16(a1, qa1, sc, 0, 0, 0);
      s16x8 b0 = *(const s16x8*)&kl1[e0[ks]];
      s16x8 b1 = *(const s16x8*)&kl1[e0[ks] ^ 32];
      f32x4 sd = __builtin_amdgcn_mfma_f32_16x16x32_bf16(b0, qb0, (f32x4){0.f,0.f,0.f,0.f}, 0, 0, 0);
      sd = __builtin_amdgcn_mfma_f32_16x16x32_bf16(b1, qb1, sd, 0, 0, 0);
      #pragma unroll
      for (int j = 0; j < 4; j++) esum[ks][j] += exp2i(sc[j]) + exp2i(sd[j]);
    }
    if (t < 7){ qa0 = qn0; qa1 = qn1; qb0 = qn2; qb1 = qn3; }
  }

  int qcol = qt*64 + w*16 + row_l;
  unsigned short* dst = invb + (size_t)b*4194304 + (size_t)qcol*2048 + kt*64 + kgrp*4;
  #pragma unroll
  for (int ks = 0; ks < 4; ks++){
    float r0 = 1.f/esum[ks][0], r1 = 1.f/esum[ks][1];
    float r2 = 1.f/esum[ks][2], r3 = 1.f/esum[ks][3];
    unsigned lo, hi;
    asm("v_cvt_pk_bf16_f32 %0, %1, %2" : "=v"(lo) : "v"(r0), "v"(r1));
    asm("v_cvt_pk_bf16_f32 %0, %1, %2" : "=v"(hi) : "v"(r2), "v"(r3));
    uint2 pk; pk.x = lo; pk.y = hi;
    *(uint2*)&dst[ks*16] = pk;
  }
}

// ---------------- PV-pass v10: 2 k-tiles per barrier-phase, ring-4 slots POST-barrier ----------------
// grid 512 = (b, h, pair i) XCD-swizzled; block runs q-tile i (i+1 tiles) then 31-i (32-i tiles).
// Iter j computes tiles 2j,2j+1 from slots (2j)&3,(2j+1)&3; post-barrier(j) stages tiles
// 2j+2,2j+3 (sources clamped to k1t-1 for constant vm counts; slot = 2j+2/2j+3 &3 = the pair
// read at iter j-1, barrier-protected). K ring-4 + V ring-4 + Ws = 73.25 KB -> 2 blocks/CU
// (= grid residency, no loss). VMCNT: j=0 -> nx?16:8; steady -> nx?8:0.
__launch_bounds__(256)
__global__ void pv_kernel(const unsigned short* __restrict__ qbuf,
                          const unsigned short* __restrict__ kb,
                          const unsigned short* __restrict__ vt,
                          const unsigned short* __restrict__ invb,
                          const float* __restrict__ sufv,
                          unsigned short* __restrict__ ab)
{
  __shared__ unsigned short Kst[4][4096];   // 32 KB
  __shared__ unsigned short Vst[4][4096];   // 32 KB
  __shared__ unsigned short Wsh[4][1152];   // 9.25 KB (per-wave private)

  int bid = blockIdx.x;                      // 512 = 8 * 64
  int blk = ((bid & 7) << 6) | (bid >> 3);   // XCD swizzle (bijective)
  int i = blk & 15;
  int h = (blk >> 4) & 15;
  int b = blk >> 8;

  int tid = threadIdx.x, lane = tid & 63, w = tid >> 6;
  int row_l = lane & 15, kgrp = lane >> 4;

  const unsigned short* KT = kb + (size_t)((b*16 + h)*32) * 4096;
  const unsigned short* VT = vt + (size_t)((b*16 + h)*32) * 4096;
  int sgoff = (w*128 + lane)*8;
  unsigned short* Wsw = &Wsh[w][0];

  int eK[4];
  #pragma unroll
  for (int ks = 0; ks < 4; ks++){
    int row = ks*16 + row_l;
    eK[ks] = (row*64 + kgrp*8) ^ ((row & 7) << 3);
  }

  auto stageK = [&](int kt, int slot){
    gll16(KT + (size_t)kt*4096 + sgoff,       (void*)(&Kst[slot][0] + w*1024));
    gll16(KT + (size_t)kt*4096 + sgoff + 512, (void*)(&Kst[slot][0] + w*1024 + 512));
  };
  auto stageV = [&](int kt, int slot){
    gll16(VT + (size_t)kt*4096 + sgoff,       (void*)(&Vst[slot][0] + w*1024));
    gll16(VT + (size_t)kt*4096 + sgoff + 512, (void*)(&Vst[slot][0] + w*1024 + 512));
  };

  auto run = [&](int qt, int k1t){            // k-range [0, k1t)
    int q0 = qt * 64;
    int qv = q0 + w*16 + row_l;
    const unsigned short* qrow_p = qbuf + (size_t)(b*2048 + qv) * 1024 + h*64;
    s16x8 qf0 = *(const s16x8*)&qrow_p[kgrp*8];
    s16x8 qf1 = *(const s16x8*)&qrow_p[32 + kgrp*8];
    SB();                                     // pin qf loads before the counted region
    const unsigned short* ivrow = invb + (size_t)b*4194304 + (size_t)qv*2048 + kgrp*4;

    f32x4 pvv[4];
    #pragma unroll
    for (int d = 0; d < 4; d++) pvv[d] = (f32x4){0.f,0.f,0.f,0.f};

    // one tile's compute: QK^T (swapped), weights, PV accumulate
    auto compute_tile = [&](int kt, int slot, s16x4* icur){
      const unsigned short* kl = &Kst[slot][0];
      const unsigned short* vl = &Vst[slot][0];
      f32x4 sc[4];
      #pragma unroll
      for (int ks = 0; ks < 4; ks++){
        s16x8 a0 = *(const s16x8*)&kl[eK[ks]];
        s16x8 a1 = *(const s16x8*)&kl[eK[ks] ^ 32];
        sc[ks] = __builtin_amdgcn_mfma_f32_16x16x32_bf16(a0, qf0, (f32x4){0.f,0.f,0.f,0.f}, 0, 0, 0);
        sc[ks] = __builtin_amdgcn_mfma_f32_16x16x32_bf16(a1, qf1, sc[ks], 0, 0, 0);
      }
      if (kt == qt){
        int kbase = kt*64 + kgrp*4;
        #pragma unroll
        for (int ks = 0; ks < 4; ks++){
          #pragma unroll
          for (int j = 0; j < 4; j++){
            float wv = exp2i(sc[ks][j]) * bf2f((unsigned short)icur[ks][j]);
            sc[ks][j] = (kbase + ks*16 + j > qv) ? 0.0625f : wv;
          }
          unsigned lo, hi;
          asm("v_cvt_pk_bf16_f32 %0, %1, %2" : "=v"(lo) : "v"(sc[ks][0]), "v"(sc[ks][1]));
          asm("v_cvt_pk_bf16_f32 %0, %1, %2" : "=v"(hi) : "v"(sc[ks][2]), "v"(sc[ks][3]));
          uint2 pk2; pk2.x = lo; pk2.y = hi;
          *(uint2*)&Wsw[row_l*72 + ks*16 + kgrp*4] = pk2;
        }
      } else {
        #pragma unroll
        for (int ks = 0; ks < 4; ks++){
          #pragma unroll
          for (int j = 0; j < 4; j++)
            sc[ks][j] = exp2i(sc[ks][j]) * bf2f((unsigned short)icur[ks][j]);
          unsigned lo, hi;
          asm("v_cvt_pk_bf16_f32 %0, %1, %2" : "=v"(lo) : "v"(sc[ks][0]), "v"(sc[ks][1]));
          asm("v_cvt_pk_bf16_f32 %0, %1, %2" : "=v"(hi) : "v"(sc[ks][2]), "v"(sc[ks][3]));
          uint2 pk2; pk2.x = lo; pk2.y = hi;
          *(uint2*)&Wsw[row_l*72 + ks*16 + kgrp*4] = pk2;
        }
      }
      #pragma unroll
      for (int kc = 0; kc < 2; kc++){
        s16x8 af = *(const s16x8*)&Wsw[row_l*72 + kc*32 + kgrp*8];
        #pragma unroll
        for (int dq = 0; dq < 4; dq++){
          s16x8 vf = *(const s16x8*)&vl[eK[dq] ^ (kc*32)];
          pvv[dq] = __builtin_amdgcn_mfma_f32_16x16x32_bf16(af, vf, pvv[dq], 0, 0, 0);
        }
      }
    };

    int NT = (k1t + 1) >> 1;
    int t1p = (1 < k1t) ? 1 : 0;               // clamped tile-1 source

    __syncthreads();                           // all waves done with previous segment's buffers
    // prologue: pair 0 into slots 0,1 (8 vm), invD pair 0 (8 vm)
    stageK(0, 0); stageK(t1p, 1);
    stageV(0, 0); stageV(t1p, 1);
    s16x4 iA[4], iB[4];
    #pragma unroll
    for (int ks = 0; ks < 4; ks++){
      iA[ks] = *(const s16x4*)&ivrow[ks*16];
      iB[ks] = *(const s16x4*)&ivrow[t1p*64 + ks*16];
    }
    SB();

    for (int j = 0; j < NT; j++){
      int t0 = 2*j;
      bool t1v = (t0 + 1 < k1t);
      bool nx = (j + 1 < NT);
      int s0 = (t0+2 < k1t) ? t0+2 : k1t-1;    // clamped sources for next pair
      int s1 = (t0+3 < k1t) ? t0+3 : k1t-1;

      s16x4 nA[4], nB[4];
      if (nx){
        #pragma unroll
        for (int ks = 0; ks < 4; ks++){
          nA[ks] = *(const s16x4*)&ivrow[s0*64 + ks*16];
          nB[ks] = *(const s16x4*)&ivrow[s1*64 + ks*16];   // 8 vm
        }
      }
      SB();
      // wait: stages(pair j) retired. newer ops: j==0 -> iA/iB(8)+[nA/nB(8)]; else -> [nA/nB(8)]
      if (j == 0){
        if (nx) VMCNT(16);
        else    VMCNT(8);
      } else {
        if (nx) VMCNT(8);
        else    VMCNT(0);
      }
      SB();
      __builtin_amdgcn_s_barrier();            // publish pair j; all compute(pair j-1) done
      SB();
      if (nx){                                  // POST-barrier: other pair-slots (read iter j-1) safe
        stageK(s0, (t0+2) & 3); stageK(s1, (t0+3) & 3);
        stageV(s0, (t0+2) & 3); stageV(s1, (t0+3) & 3);   // 8 vm
      }
      SB();

      compute_tile(t0, t0 & 3, iA);
      if (t1v) compute_tile(t0 + 1, (t0 + 1) & 3, iB);

      if (nx){
        #pragma unroll
        for (int ks = 0; ks < 4; ks++){ iA[ks] = nA[ks]; iB[ks] = nB[ks]; }
      }
    }

    // epilogue (direct): rows q = q0 + w*16 + kgrp*4 + j; cols d = dq*16 + row_l
    int tsuf = qt + 1;
    #pragma unroll
    for (int dq = 0; dq < 4; dq++){
      int d = dq*16 + row_l;
      float suf = sufv[((size_t)(b*16 + h)*33 + tsuf)*64 + d];
      #pragma unroll
      for (int j = 0; j < 4; j++){
        int qo = q0 + w*16 + kgrp*4 + j;
        ab[(size_t)(b*2048 + qo)*1024 + h*64 + d] = f2bf(pvv[dq][j] + 0.0625f * suf);
      }
    }
  };

  run(i, i + 1);
  run(31 - i, 32 - i);
}

// ---------------- host ----------------
extern "C" void kernel_launch(void* const* d_in, const int* in_sizes, int n_in,
                              void* d_out, int out_size, void* d_ws, size_t ws_size,
                              hipStream_t stream) {
  (void)in_sizes; (void)n_in; (void)out_size; (void)ws_size;
  const float* x  = (const float*)d_in[0];
  const float* Wa = (const float*)d_in[1];
  const float* ba = (const float*)d_in[2];
  const float* Wp = (const float*)d_in[3];
  const float* bp = (const float*)d_in[4];
  float* out = (float*)d_out;

  char* ws = (char*)d_ws;
  size_t off = 0;
  auto alloc = [&](size_t bytes) -> void* {
    void* p = ws + off;
    off += (bytes + 255) & ~(size_t)255;
    return p;
  };
  unsigned short* xb   = (unsigned short*)alloc((size_t)4096*1024*2);
  unsigned short* WaT  = (unsigned short*)alloc((size_t)3072*1024*2);
  unsigned short* WpT  = (unsigned short*)alloc((size_t)1024*1024*2);
  unsigned short* qbuf = (unsigned short*)alloc((size_t)4096*1024*2);
  unsigned short* ktile= (unsigned short*)alloc((size_t)4096*1024*2);
  unsigned short* vtile= (unsigned short*)alloc((size_t)4096*1024*2);
  unsigned short* abuf = (unsigned short*)alloc((size_t)4096*1024*2);
  unsigned short* invb = (unsigned short*)alloc((size_t)2*2048*2048*2); // bf16 invD
  float* sufv          = (float*)alloc((size_t)32*33*64*4);

  // 1) merged prep: x->bf16, Wa^T, Wp^T
  prep_kernel<<<6144, 256, 0, stream>>>(x, xb, Wa, WaT, Wp, WpT);

  // 2) QKV GEMM -> qbuf / ktile / vtile (V via LDS-transposed coalesced stores)
  gemm_kernel<0,128><<<dim3(24, 32), 256, 0, stream>>>(xb, WaT, ba, 3072, qbuf, ktile, vtile, nullptr);

  // 3) V suffix sums
  sufv_kernel<<<32, 256, 0, stream>>>(vtile, sufv);

  // 4) denominator pass (pairwise heads, ring-4, 8 barriers)
  dpass_kernel<<<1056, 256, 0, stream>>>(qbuf, ktile, invb);

  // 5) PV pass (2 k-tiles per barrier-phase, ring-4 slots)
  pv_kernel<<<512, 256, 0, stream>>>(qbuf, ktile, vtile, invb, sufv, abuf);

  // 6) projection GEMM (BM=64 -> 512 blocks, 2/CU)
  gemm_kernel<1,64><<<dim3(1024/128, 4096/64), 256, 0, stream>>>(abuf, WpT, bp, 1024, nullptr, nullptr, nullptr, out);
}

// Round 17
// 153.595 us; speedup vs baseline: 1.0549x; 1.0549x over previous
//
#include <hip/hip_runtime.h>

#define DI __device__ __forceinline__

typedef __attribute__((ext_vector_type(8))) short s16x8;
typedef __attribute__((ext_vector_type(4))) short s16x4;
typedef __attribute__((ext_vector_type(4))) float f32x4;

DI unsigned short f2bf(float f){
  unsigned u = __float_as_uint(f);
  u = (u + 0x7FFFu + ((u >> 16) & 1u)) >> 16;
  return (unsigned short)u;
}
DI float bf2f(unsigned short h){
  return __uint_as_float(((unsigned)h) << 16);
}
DI float exp2i(float x){ float r; asm("v_exp_f32 %0, %1" : "=v"(r) : "v"(x)); return r; }

DI void gll16(const void* g, void* l){
  __builtin_amdgcn_global_load_lds((const __attribute__((address_space(1))) void*)g,
                                   (__attribute__((address_space(3))) void*)l, 16, 0, 0);
}

#define VMCNT(n) asm volatile("s_waitcnt vmcnt(" #n ")" ::: "memory")
#define SB() __builtin_amdgcn_sched_barrier(0)

// ---------------- merged prep: x fp32->bf16, Wa^T, Wp^T ----------------
__global__ void prep_kernel(const float* __restrict__ x, unsigned short* __restrict__ xb,
                            const float* __restrict__ Wa, unsigned short* __restrict__ WaT,
                            const float* __restrict__ Wp, unsigned short* __restrict__ WpT)
{
  __shared__ float t[32][33];
  int blk = blockIdx.x, tid = threadIdx.x;
  if (blk < 2048){
    int i = blk * 256 + tid;
    const float4* p = (const float4*)x + (size_t)i * 2;
    float4 a = p[0], b = p[1];
    s16x8 o;
    o[0] = (short)f2bf(a.x); o[1] = (short)f2bf(a.y); o[2] = (short)f2bf(a.z); o[3] = (short)f2bf(a.w);
    o[4] = (short)f2bf(b.x); o[5] = (short)f2bf(b.y); o[6] = (short)f2bf(b.z); o[7] = (short)f2bf(b.w);
    ((s16x8*)xb)[i] = o;
  } else {
    const float* in; unsigned short* out; int R, C, bx, by;
    if (blk < 5120){
      int k = blk - 2048; in = Wa; out = WaT; R = 1024; C = 3072; bx = k % 96; by = k / 96;
    } else {
      int k = blk - 5120; in = Wp; out = WpT; R = 1024; C = 1024; bx = k % 32; by = k / 32;
    }
    int c0 = bx * 32, r0 = by * 32;
    int tx = tid & 31, ty = tid >> 5;  // 32 x 8
    #pragma unroll
    for (int i = 0; i < 4; i++)
      t[ty + i*8][tx] = in[(size_t)(r0 + ty + i*8) * C + c0 + tx];
    __syncthreads();
    #pragma unroll
    for (int i = 0; i < 4; i++)
      out[(size_t)(c0 + ty + i*8) * R + r0 + tx] = f2bf(t[tx][ty + i*8]);
  }
}

// ---------------- GEMM (m97 structure): C[M x N] = A[M x K] * Wt[N x K]^T + bias ----------------
template<int MODE, int BM>
__launch_bounds__(256)
__global__ void gemm_kernel(const unsigned short* __restrict__ A,
                            const unsigned short* __restrict__ Wt,
                            const float* __restrict__ bias,
                            int N,
                            unsigned short* __restrict__ qb,
                            unsigned short* __restrict__ kb,
                            unsigned short* __restrict__ vt,
                            float* __restrict__ out)
{
  constexpr int MI = BM / 32;
  constexpr int AC = BM / 32;
  const int K = 1024;
  __shared__ __align__(16) unsigned short Sm[BM*64 + 128*64];
  unsigned short* As = Sm;
  unsigned short* Bs = Sm + BM*64;

  int lin = blockIdx.y * gridDim.x + blockIdx.x;
  int chunk = (gridDim.x * gridDim.y) >> 3;
  int v = (lin & 7) * chunk + (lin >> 3);
  int bx = v % gridDim.x, by = v / gridDim.x;
  int m0 = by * BM, n0 = bx * 128;

  int tid = threadIdx.x;
  int lane = tid & 63, w = tid >> 6;
  int row_l = lane & 15, kgrp = lane >> 4;
  int wm = (w >> 1) * (MI * 16), wn = (w & 1) * 64;

  const unsigned short* asrc[AC];
  const unsigned short* bsrc[4];
  int ldsoA[AC], ldsoB[4];
  int chnk = (lane & 7) ^ (lane >> 3);
  #pragma unroll
  for (int c4 = 0; c4 < AC; c4++){
    int r = c4*32 + w*8 + (lane >> 3);
    asrc[c4] = A + (size_t)(m0 + r) * K + chnk*8;
    ldsoA[c4] = (c4*32 + w*8) * 64;
  }
  #pragma unroll
  for (int c4 = 0; c4 < 4; c4++){
    int r = c4*32 + w*8 + (lane >> 3);
    bsrc[c4] = Wt + (size_t)(n0 + r) * K + chnk*8;
    ldsoB[c4] = (c4*32 + w*8) * 64;
  }
  int eA[MI], eB[4];
  #pragma unroll
  for (int i = 0; i < MI; i++){
    int ra = wm + i*16 + row_l;
    eA[i] = (ra*64 + kgrp*8) ^ ((ra & 7) << 3);
  }
  #pragma unroll
  for (int i = 0; i < 4; i++){
    int rb = wn + i*16 + row_l;
    eB[i] = (rb*64 + kgrp*8) ^ ((rb & 7) << 3);
  }

  f32x4 acc[MI][4];
  #pragma unroll
  for (int i = 0; i < MI; i++)
    #pragma unroll
    for (int j = 0; j < 4; j++)
      acc[i][j] = (f32x4){0.f, 0.f, 0.f, 0.f};

  for (int k0 = 0; k0 < K; k0 += 64){
    #pragma unroll
    for (int c4 = 0; c4 < AC; c4++)
      gll16(asrc[c4] + k0, (void*)(As + ldsoA[c4]));
    #pragma unroll
    for (int c4 = 0; c4 < 4; c4++)
      gll16(bsrc[c4] + k0, (void*)(Bs + ldsoB[c4]));
    __syncthreads();
    #pragma unroll
    for (int kc = 0; kc < 2; kc++){
      s16x8 af[MI], bfr[4];
      #pragma unroll
      for (int mi = 0; mi < MI; mi++)
        af[mi] = *(const s16x8*)&As[eA[mi] ^ (kc*32)];
      #pragma unroll
      for (int ni = 0; ni < 4; ni++)
        bfr[ni] = *(const s16x8*)&Bs[eB[ni] ^ (kc*32)];
      #pragma unroll
      for (int mi = 0; mi < MI; mi++)
        #pragma unroll
        for (int ni = 0; ni < 4; ni++)
          acc[mi][ni] = __builtin_amdgcn_mfma_f32_16x16x32_bf16(af[mi], bfr[ni], acc[mi][ni], 0, 0, 0);
    }
    __syncthreads();
  }

  if (MODE == 0){
    unsigned long long* ldsT = (unsigned long long*)Sm;   // [np 0..127][mq 0..31] u64
    #pragma unroll
    for (int mi = 0; mi < MI; mi++){
      #pragma unroll
      for (int ni = 0; ni < 4; ni++){
        int np = wn + ni*16 + row_l;
        int gc = n0 + np;
        int hh = gc / 192, cc = gc % 192;
        float bia = bias[gc];
        if (cc < 128){
          #pragma unroll
          for (int j = 0; j < 4; j++){
            int gr = m0 + wm + mi*16 + kgrp*4 + j;
            float v2 = acc[mi][ni][j] + bia;
            if (cc < 64){
              qb[(size_t)gr * 1024 + hh*64 + cc] = f2bf(v2 * 1.44269504f);
            } else {
              int d = cc - 64; int b = gr >> 11, s = gr & 2047;
              int kt = s >> 6, kk = s & 63;
              kb[(size_t)((b*16 + hh)*32 + kt) * 4096 + ((kk*64 + d) ^ ((kk & 7) << 3))] = f2bf(v2);
            }
          }
        } else {
          float v0 = acc[mi][ni][0] + bia, v1 = acc[mi][ni][1] + bia;
          float v2 = acc[mi][ni][2] + bia, v3 = acc[mi][ni][3] + bia;
          unsigned lo, hi;
          asm("v_cvt_pk_bf16_f32 %0, %1, %2" : "=v"(lo) : "v"(v0), "v"(v1));
          asm("v_cvt_pk_bf16_f32 %0, %1, %2" : "=v"(hi) : "v"(v2), "v"(v3));
          int mq = (wm + mi*16 + kgrp*4) >> 2;
          ldsT[np*32 + (mq ^ ((np & 7) << 2))] = ((unsigned long long)hi << 32) | (unsigned long long)lo;
        }
      }
    }
    __syncthreads();
    int bb = m0 >> 11, s_base = m0 & 2047;
    for (int item = tid; item < 2048; item += 256){
      int np = item >> 4;
      int gcv = n0 + np;
      int cc = gcv % 192;
      if (cc < 128) continue;
      int d = cc - 128, hh = gcv / 192;
      int sub = (item >> 3) & 1;
      int c = item & 7;
      int mq0 = sub*16 + c*2;
      s16x8 val = *(const s16x8*)&Sm[np*128 + ((mq0 ^ ((np & 7) << 2)) << 2)];
      size_t base = ((size_t)((bb*16 + hh)*32) + (s_base >> 6) + sub) * 4096 + d*64 + ((c ^ (d & 7)) << 3);
      *(s16x8*)&vt[base] = val;
    }
  } else {
    #pragma unroll
    for (int mi = 0; mi < MI; mi++){
      #pragma unroll
      for (int ni = 0; ni < 4; ni++){
        #pragma unroll
        for (int j = 0; j < 4; j++){
          int gr = m0 + wm + mi*16 + kgrp*4 + j;
          int gc = n0 + wn + ni*16 + row_l;
          out[(size_t)gr * N + gc] = acc[mi][ni][j] + bias[gc];
        }
      }
    }
  }
}

// ---------------- V suffix sums (64-key granularity): sufv[bh][t in 0..32][64d] ----------------
__global__ void sufv_kernel(const unsigned short* __restrict__ vt, float* __restrict__ sufv){
  __shared__ float tot[4][64];
  int bh = blockIdx.x;                 // 32
  int tid = threadIdx.x;               // 256
  int tq = tid >> 6, d = tid & 63;
  const unsigned short* base = vt + (size_t)bh * 32 * 4096;
  float s[8];
  float run = 0.f;
  for (int j = 7; j >= 0; j--){
    int t = tq*8 + j;
    float rs = 0.f;
    #pragma unroll
    for (int c = 0; c < 8; c++){
      int idx = (d*64 + c*8) ^ ((d & 7) << 3);
      s16x8 v = *(const s16x8*)&base[(size_t)t*4096 + idx];
      #pragma unroll
      for (int e = 0; e < 8; e++) rs += bf2f((unsigned short)v[e]);
    }
    run += rs; s[j] = run;
  }
  tot[tq][d] = run;
  __syncthreads();
  float carry = 0.f;
  for (int t2 = tq+1; t2 < 4; t2++) carry += tot[t2][d];
  #pragma unroll
  for (int j = 0; j < 8; j++)
    sufv[((size_t)bh*33 + tq*8 + j)*64 + d] = s[j] + carry;
  if (tid < 64) sufv[((size_t)bh*33 + 32)*64 + tid] = 0.f;
}

// ---------------- D-pass v3 (R16-proven): pairwise heads, ring-4 slots, POST-barrier ----------------
__launch_bounds__(256)
__global__ void dpass_kernel(const unsigned short* __restrict__ qbuf,
                             const unsigned short* __restrict__ kb,
                             unsigned short* __restrict__ invb)
{
  __shared__ unsigned short Kst[4][4096];
  int bid = blockIdx.x;                       // 1056 = 8 * 132
  int blk = (bid & 7) * 132 + (bid >> 3);     // XCD swizzle (bijective)
  int b = blk / 528, t0 = blk % 528;
  int kt = (int)(32.5f - sqrtf(1056.25f - 2.f*t0));
  while (kt*(65-kt)/2 > t0) kt--;
  while ((kt+1)*(64-kt)/2 <= t0) kt++;
  int qt = kt + (t0 - kt*(65-kt)/2);

  int tid = threadIdx.x, lane = tid & 63, w = tid >> 6;
  int row_l = lane & 15, kgrp = lane >> 4;

  const unsigned short* ktb = kb + ((size_t)(b*16)*32 + kt) * 4096;
  int sgoff = (w*128 + lane)*8;

  auto stage = [&](int hh){
    const unsigned short* src = ktb + (size_t)hh * 131072;
    gll16(src + sgoff,       (void*)(&Kst[hh & 3][0] + w*1024));
    gll16(src + sgoff + 512, (void*)(&Kst[hh & 3][0] + w*1024 + 512));
  };

  int e0[4];
  #pragma unroll
  for (int ks = 0; ks < 4; ks++){
    int row = ks*16 + row_l;
    e0[ks] = (row*64 + kgrp*8) ^ ((row & 7) << 3);
  }

  const unsigned short* qrow_p = qbuf + (size_t)(b*2048 + qt*64 + w*16 + row_l) * 1024;

  stage(0); stage(1);
  s16x8 qa0 = *(const s16x8*)&qrow_p[kgrp*8];
  s16x8 qa1 = *(const s16x8*)&qrow_p[32 + kgrp*8];
  s16x8 qb0 = *(const s16x8*)&qrow_p[64 + kgrp*8];
  s16x8 qb1 = *(const s16x8*)&qrow_p[64 + 32 + kgrp*8];
  SB();

  f32x4 esum[4];
  #pragma unroll
  for (int ks = 0; ks < 4; ks++) esum[ks] = (f32x4){0.f,0.f,0.f,0.f};

  for (int t = 0; t < 8; t++){
    int h = 2*t;
    s16x8 qn0, qn1, qn2, qn3;
    if (t < 7){
      qn0 = *(const s16x8*)&qrow_p[(h+2)*64 + kgrp*8];
      qn1 = *(const s16x8*)&qrow_p[(h+2)*64 + 32 + kgrp*8];
      qn2 = *(const s16x8*)&qrow_p[(h+3)*64 + kgrp*8];
      qn3 = *(const s16x8*)&qrow_p[(h+3)*64 + 32 + kgrp*8];  // 4 vm
    }
    SB();
    if (t == 0)     VMCNT(8);
    else if (t < 7) VMCNT(4);
    else            VMCNT(0);
    SB();
    __builtin_amdgcn_s_barrier();
    SB();
    if (t < 7){ stage(h+2); stage(h+3); }   // POST-barrier into pair-slots read at iter t-1
    SB();

    const unsigned short* kl0 = &Kst[h & 3][0];
    const unsigned short* kl1 = &Kst[(h+1) & 3][0];
    #pragma unroll
    for (int ks = 0; ks < 4; ks++){
      s16x8 a0 = *(const s16x8*)&kl0[e0[ks]];
      s16x8 a1 = *(const s16x8*)&kl0[e0[ks] ^ 32];
      f32x4 sc = __builtin_amdgcn_mfma_f32_16x16x32_bf16(a0, qa0, (f32x4){0.f,0.f,0.f,0.f}, 0, 0, 0);
      sc = __builtin_amdgcn_mfma_f32_16x16x32_bf16(a1, qa1, sc, 0, 0, 0);
      s16x8 b0 = *(const s16x8*)&kl1[e0[ks]];
      s16x8 b1 = *(const s16x8*)&kl1[e0[ks] ^ 32];
      f32x4 sd = __builtin_amdgcn_mfma_f32_16x16x32_bf16(b0, qb0, (f32x4){0.f,0.f,0.f,0.f}, 0, 0, 0);
      sd = __builtin_amdgcn_mfma_f32_16x16x32_bf16(b1, qb1, sd, 0, 0, 0);
      #pragma unroll
      for (int j = 0; j < 4; j++) esum[ks][j] += exp2i(sc[j]) + exp2i(sd[j]);
    }
    if (t < 7){ qa0 = qn0; qa1 = qn1; qb0 = qn2; qb1 = qn3; }
  }

  int qcol = qt*64 + w*16 + row_l;
  unsigned short* dst = invb + (size_t)b*4194304 + (size_t)qcol*2048 + kt*64 + kgrp*4;
  #pragma unroll
  for (int ks = 0; ks < 4; ks++){
    float r0 = 1.f/esum[ks][0], r1 = 1.f/esum[ks][1];
    float r2 = 1.f/esum[ks][2], r3 = 1.f/esum[ks][3];
    unsigned lo, hi;
    asm("v_cvt_pk_bf16_f32 %0, %1, %2" : "=v"(lo) : "v"(r0), "v"(r1));
    asm("v_cvt_pk_bf16_f32 %0, %1, %2" : "=v"(hi) : "v"(r2), "v"(r3));
    uint2 pk; pk.x = lo; pk.y = hi;
    *(uint2*)&dst[ks*16] = pk;
  }
}

// ---------------- PV-pass v9 (R15-proven, 49.25 KB -> 3 blocks/CU) + setprio on MFMA ----------------
__launch_bounds__(256)
__global__ void pv_kernel(const unsigned short* __restrict__ qbuf,
                          const unsigned short* __restrict__ kb,
                          const unsigned short* __restrict__ vt,
                          const unsigned short* __restrict__ invb,
                          const float* __restrict__ sufv,
                          unsigned short* __restrict__ ab)
{
  __shared__ unsigned short Kst[3][4096];   // 24 KB
  __shared__ unsigned short Vst[2][4096];   // 16 KB
  __shared__ unsigned short Wsh[4][1152];   // 9.25 KB (per-wave private)

  int bid = blockIdx.x;                      // 512 = 8 * 64
  int blk = ((bid & 7) << 6) | (bid >> 3);   // XCD swizzle (bijective)
  int i = blk & 15;
  int h = (blk >> 4) & 15;
  int b = blk >> 8;

  int tid = threadIdx.x, lane = tid & 63, w = tid >> 6;
  int row_l = lane & 15, kgrp = lane >> 4;

  const unsigned short* KT = kb + (size_t)((b*16 + h)*32) * 4096;
  const unsigned short* VT = vt + (size_t)((b*16 + h)*32) * 4096;
  int sgoff = (w*128 + lane)*8;
  unsigned short* Wsw = &Wsh[w][0];

  int eK[4];
  #pragma unroll
  for (int ks = 0; ks < 4; ks++){
    int row = ks*16 + row_l;
    eK[ks] = (row*64 + kgrp*8) ^ ((row & 7) << 3);
  }

  auto stageK = [&](int kt, int buf){
    gll16(KT + (size_t)kt*4096 + sgoff,       (void*)(&Kst[buf][0] + w*1024));
    gll16(KT + (size_t)kt*4096 + sgoff + 512, (void*)(&Kst[buf][0] + w*1024 + 512));
  };
  auto stageV = [&](int kt, int buf){
    gll16(VT + (size_t)kt*4096 + sgoff,       (void*)(&Vst[buf][0] + w*1024));
    gll16(VT + (size_t)kt*4096 + sgoff + 512, (void*)(&Vst[buf][0] + w*1024 + 512));
  };

  auto run = [&](int qt, int k1t){            // k-range [0, k1t)
    int q0 = qt * 64;
    int qv = q0 + w*16 + row_l;
    const unsigned short* qrow_p = qbuf + (size_t)(b*2048 + qv) * 1024 + h*64;
    s16x8 qf0 = *(const s16x8*)&qrow_p[kgrp*8];
    s16x8 qf1 = *(const s16x8*)&qrow_p[32 + kgrp*8];
    SB();                                     // pin qf loads before the counted region
    const unsigned short* ivrow = invb + (size_t)b*4194304 + (size_t)qv*2048 + kgrp*4;

    f32x4 pvv[4];
    #pragma unroll
    for (int d = 0; d < 4; d++) pvv[d] = (f32x4){0.f,0.f,0.f,0.f};

    __syncthreads();                          // all waves done with previous segment's buffers
    stageK(0, 0);
    stageV(0, 0);
    s16x4 i1[4];
    #pragma unroll
    for (int ks = 0; ks < 4; ks++) i1[ks] = *(const s16x4*)&ivrow[ks*16];
    if (1 < k1t) stageK(1, 1);
    SB();

    for (int kt = 0; kt < k1t; kt++){
      bool nx1 = (kt + 1 < k1t), nx2 = (kt + 2 < k1t);
      bool first = (kt == 0);

      s16x4 icur[4];
      #pragma unroll
      for (int ks = 0; ks < 4; ks++) icur[ks] = i1[ks];
      if (nx1){
        #pragma unroll
        for (int ks = 0; ks < 4; ks++) i1[ks] = *(const s16x4*)&ivrow[(kt+1)*64 + ks*16];  // 4 vm
      }
      SB();
      if (first){
        if (nx1) VMCNT(10);
        else     VMCNT(4);
      } else {
        if (nx1) VMCNT(4);
        else     VMCNT(0);
      }
      SB();
      __builtin_amdgcn_s_barrier();           // publish K(kt), V(kt); all compute(kt-1) done
      SB();
      if (nx2) stageK(kt+2, (kt+2) % 3);      // POST-barrier: K(kt-1) buffer overwrite safe
      if (nx1) stageV(kt+1, (kt+1) & 1);      // POST-barrier: V(kt-1) buffer overwrite safe
      SB();

      const unsigned short* kl = &Kst[kt % 3][0];
      const unsigned short* vl = &Vst[kt & 1][0];
      f32x4 sc[4];
      __builtin_amdgcn_s_setprio(1);
      #pragma unroll
      for (int ks = 0; ks < 4; ks++){
        s16x8 a0 = *(const s16x8*)&kl[eK[ks]];
        s16x8 a1 = *(const s16x8*)&kl[eK[ks] ^ 32];
        sc[ks] = __builtin_amdgcn_mfma_f32_16x16x32_bf16(a0, qf0, (f32x4){0.f,0.f,0.f,0.f}, 0, 0, 0);
        sc[ks] = __builtin_amdgcn_mfma_f32_16x16x32_bf16(a1, qf1, sc[ks], 0, 0, 0);
      }
      __builtin_amdgcn_s_setprio(0);

      if (kt == qt){
        int kbase = kt*64 + kgrp*4;
        #pragma unroll
        for (int ks = 0; ks < 4; ks++){
          #pragma unroll
          for (int j = 0; j < 4; j++){
            float wv = exp2i(sc[ks][j]) * bf2f((unsigned short)icur[ks][j]);
            sc[ks][j] = (kbase + ks*16 + j > qv) ? 0.0625f : wv;
          }
          unsigned lo, hi;
          asm("v_cvt_pk_bf16_f32 %0, %1, %2" : "=v"(lo) : "v"(sc[ks][0]), "v"(sc[ks][1]));
          asm("v_cvt_pk_bf16_f32 %0, %1, %2" : "=v"(hi) : "v"(sc[ks][2]), "v"(sc[ks][3]));
          uint2 pk2; pk2.x = lo; pk2.y = hi;
          *(uint2*)&Wsw[row_l*72 + ks*16 + kgrp*4] = pk2;
        }
      } else {
        #pragma unroll
        for (int ks = 0; ks < 4; ks++){
          #pragma unroll
          for (int j = 0; j < 4; j++)
            sc[ks][j] = exp2i(sc[ks][j]) * bf2f((unsigned short)icur[ks][j]);
          unsigned lo, hi;
          asm("v_cvt_pk_bf16_f32 %0, %1, %2" : "=v"(lo) : "v"(sc[ks][0]), "v"(sc[ks][1]));
          asm("v_cvt_pk_bf16_f32 %0, %1, %2" : "=v"(hi) : "v"(sc[ks][2]), "v"(sc[ks][3]));
          uint2 pk2; pk2.x = lo; pk2.y = hi;
          *(uint2*)&Wsw[row_l*72 + ks*16 + kgrp*4] = pk2;
        }
      }

      __builtin_amdgcn_s_setprio(1);
      #pragma unroll
      for (int kc = 0; kc < 2; kc++){
        s16x8 af = *(const s16x8*)&Wsw[row_l*72 + kc*32 + kgrp*8];
        #pragma unroll
        for (int dq = 0; dq < 4; dq++){
          s16x8 vf = *(const s16x8*)&vl[eK[dq] ^ (kc*32)];
          pvv[dq] = __builtin_amdgcn_mfma_f32_16x16x32_bf16(af, vf, pvv[dq], 0, 0, 0);
        }
      }
      __builtin_amdgcn_s_setprio(0);
    }

    int tsuf = qt + 1;
    #pragma unroll
    for (int dq = 0; dq < 4; dq++){
      int d = dq*16 + row_l;
      float suf = sufv[((size_t)(b*16 + h)*33 + tsuf)*64 + d];
      #pragma unroll
      for (int j = 0; j < 4; j++){
        int qo = q0 + w*16 + kgrp*4 + j;
        ab[(size_t)(b*2048 + qo)*1024 + h*64 + d] = f2bf(pvv[dq][j] + 0.0625f * suf);
      }
    }
  };

  run(i, i + 1);
  run(31 - i, 32 - i);
}

// ---------------- host ----------------
extern "C" void kernel_launch(void* const* d_in, const int* in_sizes, int n_in,
                              void* d_out, int out_size, void* d_ws, size_t ws_size,
                              hipStream_t stream) {
  (void)in_sizes; (void)n_in; (void)out_size; (void)ws_size;
  const float* x  = (const float*)d_in[0];
  const float* Wa = (const float*)d_in[1];
  const float* ba = (const float*)d_in[2];
  const float* Wp = (const float*)d_in[3];
  const float* bp = (const float*)d_in[4];
  float* out = (float*)d_out;

  char* ws = (char*)d_ws;
  size_t off = 0;
  auto alloc = [&](size_t bytes) -> void* {
    void* p = ws + off;
    off += (bytes + 255) & ~(size_t)255;
    return p;
  };
  unsigned short* xb   = (unsigned short*)alloc((size_t)4096*1024*2);
  unsigned short* WaT  = (unsigned short*)alloc((size_t)3072*1024*2);
  unsigned short* WpT  = (unsigned short*)alloc((size_t)1024*1024*2);
  unsigned short* qbuf = (unsigned short*)alloc((size_t)4096*1024*2);
  unsigned short* ktile= (unsigned short*)alloc((size_t)4096*1024*2);
  unsigned short* vtile= (unsigned short*)alloc((size_t)4096*1024*2);
  unsigned short* abuf = (unsigned short*)alloc((size_t)4096*1024*2);
  unsigned short* invb = (unsigned short*)alloc((size_t)2*2048*2048*2); // bf16 invD
  float* sufv          = (float*)alloc((size_t)32*33*64*4);

  // 1) merged prep: x->bf16, Wa^T, Wp^T
  prep_kernel<<<6144, 256, 0, stream>>>(x, xb, Wa, WaT, Wp, WpT);

  // 2) QKV GEMM -> qbuf / ktile / vtile (V via LDS-transposed coalesced stores)
  gemm_kernel<0,128><<<dim3(24, 32), 256, 0, stream>>>(xb, WaT, ba, 3072, qbuf, ktile, vtile, nullptr);

  // 3) V suffix sums
  sufv_kernel<<<32, 256, 0, stream>>>(vtile, sufv);

  // 4) denominator pass (pairwise heads, ring-4, 8 barriers)
  dpass_kernel<<<1056, 256, 0, stream>>>(qbuf, ktile, invb);

  // 5) PV pass (R15-proven v9: 3 blocks/CU, one barrier/iter; + setprio on MFMA clusters)
  pv_kernel<<<512, 256, 0, stream>>>(qbuf, ktile, vtile, invb, sufv, abuf);

  // 6) projection GEMM (BM=64 -> 512 blocks, 2/CU)
  gemm_kernel<1,64><<<dim3(1024/128, 4096/64), 256, 0, stream>>>(abuf, WpT, bp, 1024, nullptr, nullptr, nullptr, out);
}

// Round 18
// 148.202 us; speedup vs baseline: 1.0933x; 1.0364x over previous
//
#include <hip/hip_runtime.h>

#define DI __device__ __forceinline__

typedef __attribute__((ext_vector_type(8))) short s16x8;
typedef __attribute__((ext_vector_type(4))) short s16x4;
typedef __attribute__((ext_vector_type(4))) float f32x4;

DI unsigned short f2bf(float f){
  unsigned u = __float_as_uint(f);
  u = (u + 0x7FFFu + ((u >> 16) & 1u)) >> 16;
  return (unsigned short)u;
}
DI float bf2f(unsigned short h){
  return __uint_as_float(((unsigned)h) << 16);
}
DI float exp2i(float x){ float r; asm("v_exp_f32 %0, %1" : "=v"(r) : "v"(x)); return r; }

DI void gll16(const void* g, void* l){
  __builtin_amdgcn_global_load_lds((const __attribute__((address_space(1))) void*)g,
                                   (__attribute__((address_space(3))) void*)l, 16, 0, 0);
}

#define VMCNT(n) asm volatile("s_waitcnt vmcnt(" #n ")" ::: "memory")
#define SB() __builtin_amdgcn_sched_barrier(0)

// ---------------- merged prep: x fp32->bf16, Wa^T, Wp^T ----------------
__global__ void prep_kernel(const float* __restrict__ x, unsigned short* __restrict__ xb,
                            const float* __restrict__ Wa, unsigned short* __restrict__ WaT,
                            const float* __restrict__ Wp, unsigned short* __restrict__ WpT)
{
  __shared__ float t[32][33];
  int blk = blockIdx.x, tid = threadIdx.x;
  if (blk < 2048){
    int i = blk * 256 + tid;
    const float4* p = (const float4*)x + (size_t)i * 2;
    float4 a = p[0], b = p[1];
    s16x8 o;
    o[0] = (short)f2bf(a.x); o[1] = (short)f2bf(a.y); o[2] = (short)f2bf(a.z); o[3] = (short)f2bf(a.w);
    o[4] = (short)f2bf(b.x); o[5] = (short)f2bf(b.y); o[6] = (short)f2bf(b.z); o[7] = (short)f2bf(b.w);
    ((s16x8*)xb)[i] = o;
  } else {
    const float* in; unsigned short* out; int R, C, bx, by;
    if (blk < 5120){
      int k = blk - 2048; in = Wa; out = WaT; R = 1024; C = 3072; bx = k % 96; by = k / 96;
    } else {
      int k = blk - 5120; in = Wp; out = WpT; R = 1024; C = 1024; bx = k % 32; by = k / 32;
    }
    int c0 = bx * 32, r0 = by * 32;
    int tx = tid & 31, ty = tid >> 5;  // 32 x 8
    #pragma unroll
    for (int i = 0; i < 4; i++)
      t[ty + i*8][tx] = in[(size_t)(r0 + ty + i*8) * C + c0 + tx];
    __syncthreads();
    #pragma unroll
    for (int i = 0; i < 4; i++)
      out[(size_t)(c0 + ty + i*8) * R + r0 + tx] = f2bf(t[tx][ty + i*8]);
  }
}

// ---------------- GEMM (m97 structure): C[M x N] = A[M x K] * Wt[N x K]^T + bias ----------------
// MODE 0 (BM=64): qkv -> qbuf rows (Q pre-scaled by log2e), ktile swz (direct),
//                 vtile swz via LDS-transposed coalesced stores. 1536 blocks -> 6/CU.
// MODE 1 (BM=32): proj -> fp32 out. 1024 blocks -> 4/CU.
template<int MODE, int BM>
__launch_bounds__(256)
__global__ void gemm_kernel(const unsigned short* __restrict__ A,
                            const unsigned short* __restrict__ Wt,
                            const float* __restrict__ bias,
                            int N,
                            unsigned short* __restrict__ qb,
                            unsigned short* __restrict__ kb,
                            unsigned short* __restrict__ vt,
                            float* __restrict__ out)
{
  constexpr int MI = BM / 32;          // m-frags per wave (per m-half)
  constexpr int AC = BM / 32;          // A staging chunk-groups
  const int K = 1024;
  __shared__ __align__(16) unsigned short Sm[BM*64 + 128*64];
  unsigned short* As = Sm;
  unsigned short* Bs = Sm + BM*64;

  int lin = blockIdx.y * gridDim.x + blockIdx.x;
  int chunk = (gridDim.x * gridDim.y) >> 3;
  int v = (lin & 7) * chunk + (lin >> 3);
  int bx = v % gridDim.x, by = v / gridDim.x;
  int m0 = by * BM, n0 = bx * 128;

  int tid = threadIdx.x;
  int lane = tid & 63, w = tid >> 6;
  int row_l = lane & 15, kgrp = lane >> 4;
  int wm = (w >> 1) * (MI * 16), wn = (w & 1) * 64;

  const unsigned short* asrc[AC];
  const unsigned short* bsrc[4];
  int ldsoA[AC], ldsoB[4];
  int chnk = (lane & 7) ^ (lane >> 3);
  #pragma unroll
  for (int c4 = 0; c4 < AC; c4++){
    int r = c4*32 + w*8 + (lane >> 3);
    asrc[c4] = A + (size_t)(m0 + r) * K + chnk*8;
    ldsoA[c4] = (c4*32 + w*8) * 64;
  }
  #pragma unroll
  for (int c4 = 0; c4 < 4; c4++){
    int r = c4*32 + w*8 + (lane >> 3);
    bsrc[c4] = Wt + (size_t)(n0 + r) * K + chnk*8;
    ldsoB[c4] = (c4*32 + w*8) * 64;
  }
  int eA[MI], eB[4];
  #pragma unroll
  for (int i = 0; i < MI; i++){
    int ra = wm + i*16 + row_l;
    eA[i] = (ra*64 + kgrp*8) ^ ((ra & 7) << 3);
  }
  #pragma unroll
  for (int i = 0; i < 4; i++){
    int rb = wn + i*16 + row_l;
    eB[i] = (rb*64 + kgrp*8) ^ ((rb & 7) << 3);
  }

  f32x4 acc[MI][4];
  #pragma unroll
  for (int i = 0; i < MI; i++)
    #pragma unroll
    for (int j = 0; j < 4; j++)
      acc[i][j] = (f32x4){0.f, 0.f, 0.f, 0.f};

  for (int k0 = 0; k0 < K; k0 += 64){
    #pragma unroll
    for (int c4 = 0; c4 < AC; c4++)
      gll16(asrc[c4] + k0, (void*)(As + ldsoA[c4]));
    #pragma unroll
    for (int c4 = 0; c4 < 4; c4++)
      gll16(bsrc[c4] + k0, (void*)(Bs + ldsoB[c4]));
    __syncthreads();
    #pragma unroll
    for (int kc = 0; kc < 2; kc++){
      s16x8 af[MI], bfr[4];
      #pragma unroll
      for (int mi = 0; mi < MI; mi++)
        af[mi] = *(const s16x8*)&As[eA[mi] ^ (kc*32)];
      #pragma unroll
      for (int ni = 0; ni < 4; ni++)
        bfr[ni] = *(const s16x8*)&Bs[eB[ni] ^ (kc*32)];
      #pragma unroll
      for (int mi = 0; mi < MI; mi++)
        #pragma unroll
        for (int ni = 0; ni < 4; ni++)
          acc[mi][ni] = __builtin_amdgcn_mfma_f32_16x16x32_bf16(af[mi], bfr[ni], acc[mi][ni], 0, 0, 0);
    }
    __syncthreads();
  }

  if (MODE == 0){
    // --- q/k direct stores + V columns into transposed LDS tile ---
    constexpr int WU = BM / 4;          // u64 row width of transposed tile
    constexpr int SWM = BM / 16 - 1;    // XOR mask source bits (multiples of 4 < WU)
    unsigned long long* ldsT = (unsigned long long*)Sm;   // [np 0..127][mq 0..WU) u64
    #pragma unroll
    for (int mi = 0; mi < MI; mi++){
      #pragma unroll
      for (int ni = 0; ni < 4; ni++){
        int np = wn + ni*16 + row_l;
        int gc = n0 + np;
        int hh = gc / 192, cc = gc % 192;
        float bia = bias[gc];
        if (cc < 128){
          #pragma unroll
          for (int j = 0; j < 4; j++){
            int gr = m0 + wm + mi*16 + kgrp*4 + j;
            float v2 = acc[mi][ni][j] + bia;
            if (cc < 64){
              qb[(size_t)gr * 1024 + hh*64 + cc] = f2bf(v2 * 1.44269504f);
            } else {
              int d = cc - 64; int b = gr >> 11, s = gr & 2047;
              int kt = s >> 6, kk = s & 63;
              kb[(size_t)((b*16 + hh)*32 + kt) * 4096 + ((kk*64 + d) ^ ((kk & 7) << 3))] = f2bf(v2);
            }
          }
        } else {
          float v0 = acc[mi][ni][0] + bia, v1 = acc[mi][ni][1] + bia;
          float v2 = acc[mi][ni][2] + bia, v3 = acc[mi][ni][3] + bia;
          unsigned lo, hi;
          asm("v_cvt_pk_bf16_f32 %0, %1, %2" : "=v"(lo) : "v"(v0), "v"(v1));
          asm("v_cvt_pk_bf16_f32 %0, %1, %2" : "=v"(hi) : "v"(v2), "v"(v3));
          int mq = (wm + mi*16 + kgrp*4) >> 2;
          ldsT[np*WU + (mq ^ ((np & SWM) << 2))] = ((unsigned long long)hi << 32) | (unsigned long long)lo;
        }
      }
    }
    __syncthreads();
    constexpr int SUBS = BM / 64;
    constexpr int ITEMS = 128 * SUBS * 8;
    int bb = m0 >> 11, s_base = m0 & 2047;
    for (int item = tid; item < ITEMS; item += 256){
      int np = item / (SUBS * 8);
      int rem = item - np * (SUBS * 8);
      int sub = rem >> 3;
      int c = rem & 7;
      int gcv = n0 + np;
      int cc = gcv % 192;
      if (cc < 128) continue;
      int d = cc - 128, hh = gcv / 192;
      int mq0 = sub*16 + c*2;
      s16x8 val = *(const s16x8*)&Sm[np*BM + ((mq0 ^ ((np & SWM) << 2)) << 2)];
      size_t base = ((size_t)((bb*16 + hh)*32) + (s_base >> 6) + sub) * 4096 + d*64 + ((c ^ (d & 7)) << 3);
      *(s16x8*)&vt[base] = val;
    }
  } else {
    #pragma unroll
    for (int mi = 0; mi < MI; mi++){
      #pragma unroll
      for (int ni = 0; ni < 4; ni++){
        #pragma unroll
        for (int j = 0; j < 4; j++){
          int gr = m0 + wm + mi*16 + kgrp*4 + j;
          int gc = n0 + wn + ni*16 + row_l;
          out[(size_t)gr * N + gc] = acc[mi][ni][j] + bias[gc];
        }
      }
    }
  }
}

// ---------------- V suffix sums (64-key granularity): sufv[bh][t in 0..32][64d] ----------------
__global__ void sufv_kernel(const unsigned short* __restrict__ vt, float* __restrict__ sufv){
  __shared__ float tot[4][64];
  int bh = blockIdx.x;                 // 32
  int tid = threadIdx.x;               // 256
  int tq = tid >> 6, d = tid & 63;
  const unsigned short* base = vt + (size_t)bh * 32 * 4096;
  float s[8];
  float run = 0.f;
  for (int j = 7; j >= 0; j--){
    int t = tq*8 + j;
    float rs = 0.f;
    #pragma unroll
    for (int c = 0; c < 8; c++){
      int idx = (d*64 + c*8) ^ ((d & 7) << 3);
      s16x8 v = *(const s16x8*)&base[(size_t)t*4096 + idx];
      #pragma unroll
      for (int e = 0; e < 8; e++) rs += bf2f((unsigned short)v[e]);
    }
    run += rs; s[j] = run;
  }
  tot[tq][d] = run;
  __syncthreads();
  float carry = 0.f;
  for (int t2 = tq+1; t2 < 4; t2++) carry += tot[t2][d];
  #pragma unroll
  for (int j = 0; j < 8; j++)
    sufv[((size_t)bh*33 + tq*8 + j)*64 + d] = s[j] + carry;
  if (tid < 64) sufv[((size_t)bh*33 + 32)*64 + tid] = 0.f;
}

// ---------------- D-pass v3 (R17-proven): pairwise heads, ring-4 slots, POST-barrier ----------------
__launch_bounds__(256)
__global__ void dpass_kernel(const unsigned short* __restrict__ qbuf,
                             const unsigned short* __restrict__ kb,
                             unsigned short* __restrict__ invb)
{
  __shared__ unsigned short Kst[4][4096];
  int bid = blockIdx.x;                       // 1056 = 8 * 132
  int blk = (bid & 7) * 132 + (bid >> 3);     // XCD swizzle (bijective)
  int b = blk / 528, t0 = blk % 528;
  int kt = (int)(32.5f - sqrtf(1056.25f - 2.f*t0));
  while (kt*(65-kt)/2 > t0) kt--;
  while ((kt+1)*(64-kt)/2 <= t0) kt++;
  int qt = kt + (t0 - kt*(65-kt)/2);

  int tid = threadIdx.x, lane = tid & 63, w = tid >> 6;
  int row_l = lane & 15, kgrp = lane >> 4;

  const unsigned short* ktb = kb + ((size_t)(b*16)*32 + kt) * 4096;
  int sgoff = (w*128 + lane)*8;

  auto stage = [&](int hh){
    const unsigned short* src = ktb + (size_t)hh * 131072;
    gll16(src + sgoff,       (void*)(&Kst[hh & 3][0] + w*1024));
    gll16(src + sgoff + 512, (void*)(&Kst[hh & 3][0] + w*1024 + 512));
  };

  int e0[4];
  #pragma unroll
  for (int ks = 0; ks < 4; ks++){
    int row = ks*16 + row_l;
    e0[ks] = (row*64 + kgrp*8) ^ ((row & 7) << 3);
  }

  const unsigned short* qrow_p = qbuf + (size_t)(b*2048 + qt*64 + w*16 + row_l) * 1024;

  stage(0); stage(1);
  s16x8 qa0 = *(const s16x8*)&qrow_p[kgrp*8];
  s16x8 qa1 = *(const s16x8*)&qrow_p[32 + kgrp*8];
  s16x8 qb0 = *(const s16x8*)&qrow_p[64 + kgrp*8];
  s16x8 qb1 = *(const s16x8*)&qrow_p[64 + 32 + kgrp*8];
  SB();

  f32x4 esum[4];
  #pragma unroll
  for (int ks = 0; ks < 4; ks++) esum[ks] = (f32x4){0.f,0.f,0.f,0.f};

  for (int t = 0; t < 8; t++){
    int h = 2*t;
    s16x8 qn0, qn1, qn2, qn3;
    if (t < 7){
      qn0 = *(const s16x8*)&qrow_p[(h+2)*64 + kgrp*8];
      qn1 = *(const s16x8*)&qrow_p[(h+2)*64 + 32 + kgrp*8];
      qn2 = *(const s16x8*)&qrow_p[(h+3)*64 + kgrp*8];
      qn3 = *(const s16x8*)&qrow_p[(h+3)*64 + 32 + kgrp*8];  // 4 vm
    }
    SB();
    if (t == 0)     VMCNT(8);
    else if (t < 7) VMCNT(4);
    else            VMCNT(0);
    SB();
    __builtin_amdgcn_s_barrier();
    SB();
    if (t < 7){ stage(h+2); stage(h+3); }   // POST-barrier into pair-slots read at iter t-1
    SB();

    const unsigned short* kl0 = &Kst[h & 3][0];
    const unsigned short* kl1 = &Kst[(h+1) & 3][0];
    #pragma unroll
    for (int ks = 0; ks < 4; ks++){
      s16x8 a0 = *(const s16x8*)&kl0[e0[ks]];
      s16x8 a1 = *(const s16x8*)&kl0[e0[ks] ^ 32];
      f32x4 sc = __builtin_amdgcn_mfma_f32_16x16x32_bf16(a0, qa0, (f32x4){0.f,0.f,0.f,0.f}, 0, 0, 0);
      sc = __builtin_amdgcn_mfma_f32_16x16x32_bf16(a1, qa1, sc, 0, 0, 0);
      s16x8 b0 = *(const s16x8*)&kl1[e0[ks]];
      s16x8 b1 = *(const s16x8*)&kl1[e0[ks] ^ 32];
      f32x4 sd = __builtin_amdgcn_mfma_f32_16x16x32_bf16(b0, qb0, (f32x4){0.f,0.f,0.f,0.f}, 0, 0, 0);
      sd = __builtin_amdgcn_mfma_f32_16x16x32_bf16(b1, qb1, sd, 0, 0, 0);
      #pragma unroll
      for (int j = 0; j < 4; j++) esum[ks][j] += exp2i(sc[j]) + exp2i(sd[j]);
    }
    if (t < 7){ qa0 = qn0; qa1 = qn1; qb0 = qn2; qb1 = qn3; }
  }

  int qcol = qt*64 + w*16 + row_l;
  unsigned short* dst = invb + (size_t)b*4194304 + (size_t)qcol*2048 + kt*64 + kgrp*4;
  #pragma unroll
  for (int ks = 0; ks < 4; ks++){
    float r0 = 1.f/esum[ks][0], r1 = 1.f/esum[ks][1];
    float r2 = 1.f/esum[ks][2], r3 = 1.f/esum[ks][3];
    unsigned lo, hi;
    asm("v_cvt_pk_bf16_f32 %0, %1, %2" : "=v"(lo) : "v"(r0), "v"(r1));
    asm("v_cvt_pk_bf16_f32 %0, %1, %2" : "=v"(hi) : "v"(r2), "v"(r3));
    uint2 pk; pk.x = lo; pk.y = hi;
    *(uint2*)&dst[ks*16] = pk;
  }
}

// ---------------- PV-pass v9.1: R15 skeleton + stageV-first post-barrier + VMCNT(6) steady ----------------
// Post-barrier order V then K => draining stageV(kt) no longer drains stageK(kt+1) early
// (true K lead-2 in drain terms). Counts: first iter nx1?10:4; steady nx1?6:0 (re-audited).
__launch_bounds__(256)
__global__ void pv_kernel(const unsigned short* __restrict__ qbuf,
                          const unsigned short* __restrict__ kb,
                          const unsigned short* __restrict__ vt,
                          const unsigned short* __restrict__ invb,
                          const float* __restrict__ sufv,
                          unsigned short* __restrict__ ab)
{
  __shared__ unsigned short Kst[3][4096];   // 24 KB
  __shared__ unsigned short Vst[2][4096];   // 16 KB
  __shared__ unsigned short Wsh[4][1152];   // 9.25 KB (per-wave private)

  int bid = blockIdx.x;                      // 512 = 8 * 64
  int blk = ((bid & 7) << 6) | (bid >> 3);   // XCD swizzle (bijective)
  int i = blk & 15;
  int h = (blk >> 4) & 15;
  int b = blk >> 8;

  int tid = threadIdx.x, lane = tid & 63, w = tid >> 6;
  int row_l = lane & 15, kgrp = lane >> 4;

  const unsigned short* KT = kb + (size_t)((b*16 + h)*32) * 4096;
  const unsigned short* VT = vt + (size_t)((b*16 + h)*32) * 4096;
  int sgoff = (w*128 + lane)*8;
  unsigned short* Wsw = &Wsh[w][0];

  int eK[4];
  #pragma unroll
  for (int ks = 0; ks < 4; ks++){
    int row = ks*16 + row_l;
    eK[ks] = (row*64 + kgrp*8) ^ ((row & 7) << 3);
  }

  auto stageK = [&](int kt, int buf){
    gll16(KT + (size_t)kt*4096 + sgoff,       (void*)(&Kst[buf][0] + w*1024));
    gll16(KT + (size_t)kt*4096 + sgoff + 512, (void*)(&Kst[buf][0] + w*1024 + 512));
  };
  auto stageV = [&](int kt, int buf){
    gll16(VT + (size_t)kt*4096 + sgoff,       (void*)(&Vst[buf][0] + w*1024));
    gll16(VT + (size_t)kt*4096 + sgoff + 512, (void*)(&Vst[buf][0] + w*1024 + 512));
  };

  auto run = [&](int qt, int k1t){            // k-range [0, k1t)
    int q0 = qt * 64;
    int qv = q0 + w*16 + row_l;
    const unsigned short* qrow_p = qbuf + (size_t)(b*2048 + qv) * 1024 + h*64;
    s16x8 qf0 = *(const s16x8*)&qrow_p[kgrp*8];
    s16x8 qf1 = *(const s16x8*)&qrow_p[32 + kgrp*8];
    SB();                                     // pin qf loads before the counted region
    const unsigned short* ivrow = invb + (size_t)b*4194304 + (size_t)qv*2048 + kgrp*4;

    f32x4 pvv[4];
    #pragma unroll
    for (int d = 0; d < 4; d++) pvv[d] = (f32x4){0.f,0.f,0.f,0.f};

    __syncthreads();                          // all waves done with previous segment's buffers
    stageK(0, 0);
    stageV(0, 0);
    s16x4 i1[4];
    #pragma unroll
    for (int ks = 0; ks < 4; ks++) i1[ks] = *(const s16x4*)&ivrow[ks*16];
    if (1 < k1t) stageK(1, 1);
    SB();

    for (int kt = 0; kt < k1t; kt++){
      bool nx1 = (kt + 1 < k1t), nx2 = (kt + 2 < k1t);
      bool first = (kt == 0);

      s16x4 icur[4];
      #pragma unroll
      for (int ks = 0; ks < 4; ks++) icur[ks] = i1[ks];
      if (nx1){
        #pragma unroll
        for (int ks = 0; ks < 4; ks++) i1[ks] = *(const s16x4*)&ivrow[(kt+1)*64 + ks*16];  // 4 vm
      }
      SB();
      if (first){
        if (nx1) VMCNT(10);
        else     VMCNT(4);
      } else {
        if (nx1) VMCNT(6);    // leaves stageK(kt+1)(2) + inv(4) in flight; stageV(kt) retired
        else     VMCNT(0);
      }
      SB();
      __builtin_amdgcn_s_barrier();           // publish K(kt), V(kt); all compute(kt-1) done
      SB();
      if (nx1) stageV(kt+1, (kt+1) & 1);      // POST-barrier FIRST: V(kt-1) overwrite safe
      if (nx2) stageK(kt+2, (kt+2) % 3);      // POST-barrier: K(kt-1) buffer overwrite safe
      SB();

      const unsigned short* kl = &Kst[kt % 3][0];
      const unsigned short* vl = &Vst[kt & 1][0];
      f32x4 sc[4];
      __builtin_amdgcn_s_setprio(1);
      #pragma unroll
      for (int ks = 0; ks < 4; ks++){
        s16x8 a0 = *(const s16x8*)&kl[eK[ks]];
        s16x8 a1 = *(const s16x8*)&kl[eK[ks] ^ 32];
        sc[ks] = __builtin_amdgcn_mfma_f32_16x16x32_bf16(a0, qf0, (f32x4){0.f,0.f,0.f,0.f}, 0, 0, 0);
        sc[ks] = __builtin_amdgcn_mfma_f32_16x16x32_bf16(a1, qf1, sc[ks], 0, 0, 0);
      }
      __builtin_amdgcn_s_setprio(0);

      if (kt == qt){
        int kbase = kt*64 + kgrp*4;
        #pragma unroll
        for (int ks = 0; ks < 4; ks++){
          #pragma unroll
          for (int j = 0; j < 4; j++){
            float wv = exp2i(sc[ks][j]) * bf2f((unsigned short)icur[ks][j]);
            sc[ks][j] = (kbase + ks*16 + j > qv) ? 0.0625f : wv;
          }
          unsigned lo, hi;
          asm("v_cvt_pk_bf16_f32 %0, %1, %2" : "=v"(lo) : "v"(sc[ks][0]), "v"(sc[ks][1]));
          asm("v_cvt_pk_bf16_f32 %0, %1, %2" : "=v"(hi) : "v"(sc[ks][2]), "v"(sc[ks][3]));
          uint2 pk2; pk2.x = lo; pk2.y = hi;
          *(uint2*)&Wsw[row_l*72 + ks*16 + kgrp*4] = pk2;
        }
      } else {
        #pragma unroll
        for (int ks = 0; ks < 4; ks++){
          #pragma unroll
          for (int j = 0; j < 4; j++)
            sc[ks][j] = exp2i(sc[ks][j]) * bf2f((unsigned short)icur[ks][j]);
          unsigned lo, hi;
          asm("v_cvt_pk_bf16_f32 %0, %1, %2" : "=v"(lo) : "v"(sc[ks][0]), "v"(sc[ks][1]));
          asm("v_cvt_pk_bf16_f32 %0, %1, %2" : "=v"(hi) : "v"(sc[ks][2]), "v"(sc[ks][3]));
          uint2 pk2; pk2.x = lo; pk2.y = hi;
          *(uint2*)&Wsw[row_l*72 + ks*16 + kgrp*4] = pk2;
        }
      }

      __builtin_amdgcn_s_setprio(1);
      #pragma unroll
      for (int kc = 0; kc < 2; kc++){
        s16x8 af = *(const s16x8*)&Wsw[row_l*72 + kc*32 + kgrp*8];
        #pragma unroll
        for (int dq = 0; dq < 4; dq++){
          s16x8 vf = *(const s16x8*)&vl[eK[dq] ^ (kc*32)];
          pvv[dq] = __builtin_amdgcn_mfma_f32_16x16x32_bf16(af, vf, pvv[dq], 0, 0, 0);
        }
      }
      __builtin_amdgcn_s_setprio(0);
    }

    int tsuf = qt + 1;
    #pragma unroll
    for (int dq = 0; dq < 4; dq++){
      int d = dq*16 + row_l;
      float suf = sufv[((size_t)(b*16 + h)*33 + tsuf)*64 + d];
      #pragma unroll
      for (int j = 0; j < 4; j++){
        int qo = q0 + w*16 + kgrp*4 + j;
        ab[(size_t)(b*2048 + qo)*1024 + h*64 + d] = f2bf(pvv[dq][j] + 0.0625f * suf);
      }
    }
  };

  run(i, i + 1);
  run(31 - i, 32 - i);
}

// ---------------- host ----------------
extern "C" void kernel_launch(void* const* d_in, const int* in_sizes, int n_in,
                              void* d_out, int out_size, void* d_ws, size_t ws_size,
                              hipStream_t stream) {
  (void)in_sizes; (void)n_in; (void)out_size; (void)ws_size;
  const float* x  = (const float*)d_in[0];
  const float* Wa = (const float*)d_in[1];
  const float* ba = (const float*)d_in[2];
  const float* Wp = (const float*)d_in[3];
  const float* bp = (const float*)d_in[4];
  float* out = (float*)d_out;

  char* ws = (char*)d_ws;
  size_t off = 0;
  auto alloc = [&](size_t bytes) -> void* {
    void* p = ws + off;
    off += (bytes + 255) & ~(size_t)255;
    return p;
  };
  unsigned short* xb   = (unsigned short*)alloc((size_t)4096*1024*2);
  unsigned short* WaT  = (unsigned short*)alloc((size_t)3072*1024*2);
  unsigned short* WpT  = (unsigned short*)alloc((size_t)1024*1024*2);
  unsigned short* qbuf = (unsigned short*)alloc((size_t)4096*1024*2);
  unsigned short* ktile= (unsigned short*)alloc((size_t)4096*1024*2);
  unsigned short* vtile= (unsigned short*)alloc((size_t)4096*1024*2);
  unsigned short* abuf = (unsigned short*)alloc((size_t)4096*1024*2);
  unsigned short* invb = (unsigned short*)alloc((size_t)2*2048*2048*2); // bf16 invD
  float* sufv          = (float*)alloc((size_t)32*33*64*4);

  // 1) merged prep: x->bf16, Wa^T, Wp^T
  prep_kernel<<<6144, 256, 0, stream>>>(x, xb, Wa, WaT, Wp, WpT);

  // 2) QKV GEMM (BM=64 -> 1536 blocks, 6/CU) -> qbuf / ktile / vtile
  gemm_kernel<0,64><<<dim3(24, 64), 256, 0, stream>>>(xb, WaT, ba, 3072, qbuf, ktile, vtile, nullptr);

  // 3) V suffix sums
  sufv_kernel<<<32, 256, 0, stream>>>(vtile, sufv);

  // 4) denominator pass (pairwise heads, ring-4, 8 barriers)
  dpass_kernel<<<1056, 256, 0, stream>>>(qbuf, ktile, invb);

  // 5) PV pass (v9.1: stageV-first post-barrier, VMCNT 6 steady)
  pv_kernel<<<512, 256, 0, stream>>>(qbuf, ktile, vtile, invb, sufv, abuf);

  // 6) projection GEMM (BM=32 -> 1024 blocks, 4/CU)
  gemm_kernel<1,32><<<dim3(8, 128), 256, 0, stream>>>(abuf, WpT, bp, 1024, nullptr, nullptr, nullptr, out);
}